// Round 7
// baseline (127.899 us; speedup 1.0000x reference)
//
#include <hip/hip_runtime.h>

typedef _Float16 f16;
typedef _Float16 f16x8 __attribute__((ext_vector_type(8)));
typedef _Float16 f16x4 __attribute__((ext_vector_type(4)));
typedef float f32x4 __attribute__((ext_vector_type(4)));
typedef float f32x16 __attribute__((ext_vector_type(16)));

#define MFMA_F16(a, b, c) __builtin_amdgcn_mfma_f32_16x16x32_f16(a, b, c, 0, 0, 0)
#define MFMA32(a, b, c) __builtin_amdgcn_mfma_f32_32x32x16_f16(a, b, c, 0, 0, 0)

__device__ __forceinline__ void gld16(const void* g, void* l) {
  __builtin_amdgcn_global_load_lds(
      (const __attribute__((address_space(1))) unsigned int*)(unsigned long long)g,
      (__attribute__((address_space(3))) unsigned int*)(unsigned long long)l, 16, 0, 0);
}

__device__ __forceinline__ int pkrtz(float a, float b) {
  return __builtin_bit_cast(int, __builtin_amdgcn_cvt_pkrtz(a, b));
}

union U8 { int i[4]; f16x8 v; };

// ---------------------------------------------------------------- conversions
__global__ __launch_bounds__(256) void cvt_x_kernel(const float* __restrict__ in,
                                                    f16* __restrict__ out, int n8) {
  int i = blockIdx.x * 256 + threadIdx.x;
  if (i >= n8) return;
  const float4* p = (const float4*)(in + (size_t)i * 8);
  float4 a = p[0], b = p[1];
  f16x8 o = {(f16)a.x, (f16)a.y, (f16)a.z, (f16)a.w,
             (f16)b.x, (f16)b.y, (f16)b.z, (f16)b.w};
  *(f16x8*)(out + (size_t)i * 8) = o;
}

__global__ __launch_bounds__(256) void cvt_w4_kernel(const float* __restrict__ w0,
                                                     const float* __restrict__ w1,
                                                     const float* __restrict__ w2,
                                                     const float* __restrict__ w3,
                                                     f16* __restrict__ out) {
  int i = blockIdx.x * 256 + threadIdx.x;
  int t = i >> 17, r = i & 131071;
  const float* w = (t == 0) ? w0 : (t == 1) ? w1 : (t == 2) ? w2 : w3;
  const float4* p = (const float4*)(w + (size_t)r * 8);
  float4 a = p[0], b = p[1];
  f16x8 o = {(f16)a.x, (f16)a.y, (f16)a.z, (f16)a.w,
             (f16)b.x, (f16)b.y, (f16)b.z, (f16)b.w};
  *(f16x8*)(out + (size_t)t * 1048576 + (size_t)r * 8) = o;
}

// -------------------------------------------------- fused QKV GEMM, 2-phase
__global__ __launch_bounds__(256) void qkv_gemm_kernel(
    const f16* __restrict__ A, const f16* __restrict__ Wq,
    const f16* __restrict__ Wk, const f16* __restrict__ Wv,
    f16* __restrict__ Qo, f16* __restrict__ Ko, f16* __restrict__ VT) {
  __shared__ __align__(16) f16 As[2][128 * 64];
  __shared__ __align__(16) f16 Bs[2][128 * 64];
  const int bid = blockIdx.x + blockIdx.y * 8;
  const int swz = (bid & 7) * 80 + (bid >> 3);
  const int bx = swz & 7, y = swz >> 3;
  const f16* Bw;
  f16* Co = nullptr;
  int mt, isv = 0;
  if (y < 16) { Bw = Wq; Co = Qo; mt = (y & 7) | ((y >> 3) << 4); }
  else if (y < 48) { Bw = Wk; Co = Ko; mt = y - 16; }
  else { Bw = Wv; isv = 1; mt = y - 48; }
  const int m0 = mt * 128, n0 = bx * 128;
  const int tid = threadIdx.x, lane = tid & 63, w = tid >> 6;
  const int wr = w >> 1, wc = w & 1, g = lane >> 4, c = lane & 15;
  const int r_st = tid >> 3, t_st = tid & 7;

  auto stage = [&](int k0, int buf) {
#pragma unroll
    for (int i = 0; i < 4; ++i) {
      int row = r_st + i * 32;
      int sl = (t_st ^ (row & 7)) * 8;
      gld16(&A[(size_t)(m0 + row) * 1024 + k0 + sl], &As[buf][(row * 8 + t_st) * 8]);
      gld16(&Bw[(size_t)(n0 + row) * 1024 + k0 + sl], &Bs[buf][(row * 8 + t_st) * 8]);
    }
  };

  f32x4 acc[4][4] = {};

  stage(0, 0);
  __syncthreads();

  for (int t = 0; t < 16; ++t) {
    const int cur = t & 1;
    if (t < 15) stage((t + 1) * 64, cur ^ 1);
#pragma unroll
    for (int kb = 0; kb < 2; ++kb) {
      f16x8 af[4], bf[4];
#pragma unroll
      for (int m2 = 0; m2 < 4; ++m2)
        af[m2] = *(const f16x8*)&As[cur][(wr * 64 + m2 * 16 + c) * 64 +
                                         (((kb * 4 + g) ^ (c & 7)) * 8)];
#pragma unroll
      for (int nt = 0; nt < 4; ++nt)
        bf[nt] = *(const f16x8*)&Bs[cur][(wc * 64 + nt * 16 + c) * 64 +
                                         (((kb * 4 + g) ^ (c & 7)) * 8)];
#pragma unroll
      for (int m2 = 0; m2 < 4; ++m2)
#pragma unroll
        for (int nt = 0; nt < 4; ++nt)
          acc[m2][nt] = MFMA_F16(af[m2], bf[nt], acc[m2][nt]);
    }
    __syncthreads();
  }

  if (isv) {
    const int b = m0 >> 11;
    const int n_base = (m0 & 2047) + wr * 64 + g * 4;
#pragma unroll
    for (int m2 = 0; m2 < 4; ++m2)
#pragma unroll
      for (int nt = 0; nt < 4; ++nt) {
        int col = n0 + wc * 64 + nt * 16 + c;
        int h = col >> 6, d = col & 63;
        f16x4 pv = {(f16)acc[m2][nt][0], (f16)acc[m2][nt][1],
                    (f16)acc[m2][nt][2], (f16)acc[m2][nt][3]};
        *(f16x4*)&VT[((size_t)((b * 16 + h) * 64 + d)) * 2048 + n_base + m2 * 16] = pv;
      }
  } else {
#pragma unroll
    for (int m2 = 0; m2 < 4; ++m2)
#pragma unroll
      for (int nt = 0; nt < 4; ++nt) {
        int col = n0 + wc * 64 + nt * 16 + c;
#pragma unroll
        for (int r = 0; r < 4; ++r)
          Co[(size_t)(m0 + wr * 64 + m2 * 16 + g * 4 + r) * 1024 + col] =
              (f16)acc[m2][nt][r];
      }
  }
}

// ------------------------------------------------- proj GEMM 64x64, 2-phase
__global__ __launch_bounds__(256) void proj_gemm_kernel(
    const f16* __restrict__ A, const f16* __restrict__ Bw,
    float* __restrict__ C, const float* __restrict__ bias) {
  __shared__ __align__(16) f16 As[2][64 * 64];
  __shared__ __align__(16) f16 Bs[2][64 * 64];
  const int bid = blockIdx.x + blockIdx.y * 16;
  const int swz = (bid & 7) * 64 + (bid >> 3);
  const int m0 = (swz >> 4) * 64, n0 = (swz & 15) * 64;
  const int tid = threadIdx.x, lane = tid & 63, w = tid >> 6;
  const int wr = w >> 1, wc = w & 1, g = lane >> 4, c = lane & 15;
  const int r_st = tid >> 3, t_st = tid & 7;

  auto stage = [&](int k0, int buf) {
#pragma unroll
    for (int i = 0; i < 2; ++i) {
      int row = r_st + i * 32;
      int sl = (t_st ^ (row & 7)) * 8;
      gld16(&A[(size_t)(m0 + row) * 1024 + k0 + sl], &As[buf][(row * 8 + t_st) * 8]);
      gld16(&Bw[(size_t)(n0 + row) * 1024 + k0 + sl], &Bs[buf][(row * 8 + t_st) * 8]);
    }
  };

  f32x4 acc[2][2] = {};

  stage(0, 0);
  __syncthreads();

  for (int t = 0; t < 16; ++t) {
    const int cur = t & 1;
    if (t < 15) stage((t + 1) * 64, cur ^ 1);
#pragma unroll
    for (int kb = 0; kb < 2; ++kb) {
      f16x8 af[2], bf[2];
#pragma unroll
      for (int m2 = 0; m2 < 2; ++m2)
        af[m2] = *(const f16x8*)&As[cur][(wr * 32 + m2 * 16 + c) * 64 +
                                         (((kb * 4 + g) ^ (c & 7)) * 8)];
#pragma unroll
      for (int nt = 0; nt < 2; ++nt)
        bf[nt] = *(const f16x8*)&Bs[cur][(wc * 32 + nt * 16 + c) * 64 +
                                         (((kb * 4 + g) ^ (c & 7)) * 8)];
#pragma unroll
      for (int m2 = 0; m2 < 2; ++m2)
#pragma unroll
        for (int nt = 0; nt < 2; ++nt)
          acc[m2][nt] = MFMA_F16(af[m2], bf[nt], acc[m2][nt]);
    }
    __syncthreads();
  }

#pragma unroll
  for (int m2 = 0; m2 < 2; ++m2)
#pragma unroll
    for (int nt = 0; nt < 2; ++nt) {
      int col = n0 + wc * 32 + nt * 16 + c;
      float bv = bias[col];
#pragma unroll
      for (int r = 0; r < 4; ++r)
        C[(size_t)(m0 + wr * 32 + m2 * 16 + g * 4 + r) * 1024 + col] =
            acc[m2][nt][r] + bv;
    }
}

// -------------------------------------------------------------- attention
// LDS-free main loop. 2048 blocks (16 qt x 16 h x 2 b x 4 ch, XCD-swizzled).
// Wave (kh,qh) owns 32k x 32q; mfma_32x32x16. K/V/Q fragments straight from
// global (L2-resident) to VGPRs; P kept in registers via cvt_pkrtz +
// shfl_xor(32) + half-select (S^T C-layout -> PV B-layout). No barriers until
// the per-chunk epilogue: cross-kh O/l reduce + transpose in LDS.
__global__ __launch_bounds__(256) void attn_kernel(const f16* __restrict__ Q,
                                                   const f16* __restrict__ Kg,
                                                   const f16* __restrict__ VT,
                                                   f16* __restrict__ Opart,
                                                   float* __restrict__ ML) {
  __shared__ float Ored[2][64][32];  // [qh][d][q] f32 partials (kh=1)
  __shared__ float Lred[2][2][32];   // [qh][kh][q]
  __shared__ f16 Otr[2][32][70];     // [qh][q][d] transpose staging
  const int flat = blockIdx.x;
  const int swz = (flat & 7) * 256 + (flat >> 3);
  const int qt = swz & 15, h = (swz >> 4) & 15;
  const int ch = (swz >> 8) & 3, b = swz >> 10;
  const int tid = threadIdx.x, lane = tid & 63, w = tid >> 6;
  const int kh = w & 1, qh = w >> 1;
  const int l31 = lane & 31, h5 = lane >> 5;
  const bool lo = lane < 32;

  const f16* Kp =
      Kg + (size_t)(b * 2048 + ch * 512 + kh * 32 + l31) * 1024 + h * 64 + h5 * 8;
  const f16* Vp = VT + ((size_t)((b * 16 + h) * 64 + l31)) * 2048 + ch * 512 +
                  kh * 32 + h5 * 8;
  const f16* Qp =
      Q + (size_t)(b * 2048 + qt * 64 + qh * 32 + l31) * 1024 + h * 64 + h5 * 8;

  // Q fragments (B-operand), scaled by SCALE*log2(e)
  f16x8 qf[4];
#pragma unroll
  for (int ks = 0; ks < 4; ++ks) {
    qf[ks] = *(const f16x8*)(Qp + ks * 16);
#pragma unroll
    for (int j = 0; j < 8; ++j)
      qf[ks][j] = (f16)((float)qf[ks][j] * 0.1803368801f);
  }

  f16x8 kc0, kc1, kc2, kc3, vc0, vc1, vc2, vc3;
  auto loadK = [&](int t) {
    const f16* p = Kp + (size_t)t * 65536;
    kc0 = *(const f16x8*)(p);
    kc1 = *(const f16x8*)(p + 16);
    kc2 = *(const f16x8*)(p + 32);
    kc3 = *(const f16x8*)(p + 48);
  };
  auto loadV = [&](int t) {
    const f16* p = Vp + t * 64;
    vc0 = *(const f16x8*)(p);          // dt0 ks0
    vc1 = *(const f16x8*)(p + 16);     // dt0 ks1
    vc2 = *(const f16x8*)(p + 65536);  // dt1 ks0
    vc3 = *(const f16x8*)(p + 65536 + 16);
  };

  f32x16 o0 = {}, o1 = {};
  float lp = 0.f;

  loadK(0);
  loadV(0);

  for (int t = 0; t < 8; ++t) {
    // S^T[32k x 32q] = K-slice * Q^T
    f32x16 s = {};
    s = MFMA32(kc0, qf[0], s);
    s = MFMA32(kc1, qf[1], s);
    s = MFMA32(kc2, qf[2], s);
    s = MFMA32(kc3, qf[3], s);
    if (t < 7) loadK(t + 1);  // refill freed regs; ~full iteration to hide

    float e[16];
#pragma unroll
    for (int i = 0; i < 16; ++i) {
      e[i] = exp2f(s[i]);
      lp += e[i];
    }
    // pack P to f16 and redistribute to mfma B-layout (k=(l>>5)*8+j)
    int c01 = pkrtz(e[0], e[1]), c23 = pkrtz(e[2], e[3]);
    int c45 = pkrtz(e[4], e[5]), c67 = pkrtz(e[6], e[7]);
    int d01 = pkrtz(e[8], e[9]), d23 = pkrtz(e[10], e[11]);
    int d45 = pkrtz(e[12], e[13]), d67 = pkrtz(e[14], e[15]);
    int xc01 = __shfl_xor(c01, 32), xc23 = __shfl_xor(c23, 32);
    int xc45 = __shfl_xor(c45, 32), xc67 = __shfl_xor(c67, 32);
    int xd01 = __shfl_xor(d01, 32), xd23 = __shfl_xor(d23, 32);
    int xd45 = __shfl_xor(d45, 32), xd67 = __shfl_xor(d67, 32);
    U8 pb0, pb1;
    pb0.i[0] = lo ? c01 : xc45;
    pb0.i[1] = lo ? c23 : xc67;
    pb0.i[2] = lo ? xc01 : c45;
    pb0.i[3] = lo ? xc23 : c67;
    pb1.i[0] = lo ? d01 : xd45;
    pb1.i[1] = lo ? d23 : xd67;
    pb1.i[2] = lo ? xd01 : d45;
    pb1.i[3] = lo ? xd23 : d67;

    // O^T[64d x 32q] += V^T-slice * P^T-slice
    o0 = MFMA32(vc0, pb0.v, o0);
    o0 = MFMA32(vc1, pb1.v, o0);
    o1 = MFMA32(vc2, pb0.v, o1);
    o1 = MFMA32(vc3, pb1.v, o1);
    if (t < 7) loadV(t + 1);
  }

  // ---- epilogue: cross-kh reduce, normalize, transpose, store
  float l_own = lp + __shfl_xor(lp, 32);
  if (kh == 1) {
#pragma unroll
    for (int reg = 0; reg < 16; ++reg) {
      int row = (reg & 3) + 8 * (reg >> 2) + 4 * h5;
      Ored[qh][row][l31] = o0[reg];
      Ored[qh][32 + row][l31] = o1[reg];
    }
    if (lo) Lred[qh][1][l31] = l_own;
  } else {
    if (lo) Lred[qh][0][l31] = l_own;
  }
  __syncthreads();
  if (kh == 0) {
    float lt = Lred[qh][0][l31] + Lred[qh][1][l31];
    float li = 1.f / lt;
#pragma unroll
    for (int reg = 0; reg < 16; ++reg) {
      int row = (reg & 3) + 8 * (reg >> 2) + 4 * h5;
      Otr[qh][l31][row] = (f16)((o0[reg] + Ored[qh][row][l31]) * li);
      Otr[qh][l31][32 + row] = (f16)((o1[reg] + Ored[qh][32 + row][l31]) * li);
    }
    // wave-internal LDS visibility (compiler inserts lgkmcnt wait)
#pragma unroll
    for (int rep = 0; rep < 4; ++rep) {
      f16x8 ov = *(const f16x8*)&Otr[qh][lane >> 1][(lane & 1) * 32 + rep * 8];
      *(f16x8*)&Opart[(size_t)ch * 2097152 +
                      (size_t)(b * 1024 + qt * 64 + qh * 32 + (lane >> 1)) * 1024 +
                      h * 64 + (lane & 1) * 32 + rep * 8] = ov;
    }
    if (lo)
      ML[ch * 32768 + (b * 1024 + qt * 64 + qh * 32 + l31) * 16 + h] = lt;
  }
}

// -------------------------------------------------------------- combine (4 chunks)
__global__ __launch_bounds__(256) void combine_kernel(const f16* __restrict__ Opart,
                                                      const float* __restrict__ ML,
                                                      f16* __restrict__ O16) {
  int i = blockIdx.x * 256 + threadIdx.x;
  int row = i >> 7;
  int h = (i & 127) >> 3;
  float l0 = ML[row * 16 + h];
  float l1 = ML[32768 + row * 16 + h];
  float l2 = ML[65536 + row * 16 + h];
  float l3 = ML[98304 + row * 16 + h];
  float inv = 1.f / (l0 + l1 + l2 + l3);
  f16x8 o0 = *(const f16x8*)&Opart[(size_t)i * 8];
  f16x8 o1 = *(const f16x8*)&Opart[2097152 + (size_t)i * 8];
  f16x8 o2 = *(const f16x8*)&Opart[4194304 + (size_t)i * 8];
  f16x8 o3 = *(const f16x8*)&Opart[6291456 + (size_t)i * 8];
  f16x8 r;
#pragma unroll
  for (int j = 0; j < 8; ++j)
    r[j] = (f16)((l0 * (float)o0[j] + l1 * (float)o1[j] + l2 * (float)o2[j] +
                  l3 * (float)o3[j]) * inv);
  *(f16x8*)&O16[(size_t)i * 8] = r;
}

// ---------------------------------------------------------------- launcher
extern "C" void kernel_launch(void* const* d_in, const int* in_sizes, int n_in,
                              void* d_out, int out_size, void* d_ws, size_t ws_size,
                              hipStream_t stream) {
  const float* x = (const float*)d_in[0];
  const float* wq = (const float*)d_in[1];
  const float* wk = (const float*)d_in[2];
  const float* wv = (const float*)d_in[3];
  const float* wp = (const float*)d_in[4];
  const float* bp = (const float*)d_in[5];
  float* out = (float*)d_out;

  char* p = (char*)d_ws;
  f16* x16 = (f16*)p;   p += (size_t)4194304 * 2;      // ML aliases after GEMMs
  f16* w16 = (f16*)p;   p += (size_t)4 * 1048576 * 2;
  f16* Q16 = (f16*)p;   p += (size_t)4194304 * 2;
  f16* K16 = (f16*)p;   p += (size_t)4194304 * 2;
  f16* VT16 = (f16*)p;  p += (size_t)4194304 * 2;      // [B,H,D,N]
  f16* Opart = (f16*)p; p += (size_t)8388608 * 2;      // 4 chunks x [B*Nq, C]
  f16* O16 = (f16*)p;   p += (size_t)2097152 * 2;

  f16* wq16 = w16;
  f16* wk16 = w16 + 1048576;
  f16* wv16 = w16 + 2 * 1048576;
  f16* wp16 = w16 + 3 * 1048576;

  cvt_x_kernel<<<4194304 / 8 / 256, 256, 0, stream>>>(x, x16, 4194304 / 8);
  cvt_w4_kernel<<<4 * 131072 / 256, 256, 0, stream>>>(wq, wk, wv, wp, w16);

  qkv_gemm_kernel<<<dim3(8, 80), 256, 0, stream>>>(x16, wq16, wk16, wv16, Q16, K16,
                                                   VT16);

  float* MLp = (float*)x16;
  attn_kernel<<<dim3(2048), 256, 0, stream>>>(Q16, K16, VT16, Opart, MLp);
  combine_kernel<<<1024, 256, 0, stream>>>(Opart, MLp, O16);

  proj_gemm_kernel<<<dim3(16, 32), 256, 0, stream>>>(O16, wp16, out, bp);
}

// Round 8
// 99.214 us; speedup vs baseline: 1.2891x; 1.2891x over previous
//
#include <hip/hip_runtime.h>

typedef _Float16 f16;
typedef _Float16 f16x8 __attribute__((ext_vector_type(8)));
typedef _Float16 f16x4 __attribute__((ext_vector_type(4)));
typedef float f32x4 __attribute__((ext_vector_type(4)));
typedef float f32x16 __attribute__((ext_vector_type(16)));

#define MFMA_F16(a, b, c) __builtin_amdgcn_mfma_f32_16x16x32_f16(a, b, c, 0, 0, 0)
#define MFMA32(a, b, c) __builtin_amdgcn_mfma_f32_32x32x16_f16(a, b, c, 0, 0, 0)

__device__ __forceinline__ void gld16(const void* g, void* l) {
  __builtin_amdgcn_global_load_lds(
      (const __attribute__((address_space(1))) unsigned int*)(unsigned long long)g,
      (__attribute__((address_space(3))) unsigned int*)(unsigned long long)l, 16, 0, 0);
}

__device__ __forceinline__ int pkrtz(float a, float b) {
  return __builtin_bit_cast(int, __builtin_amdgcn_cvt_pkrtz(a, b));
}

union U8 { int i[4]; f16x8 v; };

// ---------------------------------------------------------------- conversions
__global__ __launch_bounds__(256) void cvt_x_kernel(const float* __restrict__ in,
                                                    f16* __restrict__ out, int n8) {
  int i = blockIdx.x * 256 + threadIdx.x;
  if (i >= n8) return;
  const float4* p = (const float4*)(in + (size_t)i * 8);
  float4 a = p[0], b = p[1];
  f16x8 o = {(f16)a.x, (f16)a.y, (f16)a.z, (f16)a.w,
             (f16)b.x, (f16)b.y, (f16)b.z, (f16)b.w};
  *(f16x8*)(out + (size_t)i * 8) = o;
}

__global__ __launch_bounds__(256) void cvt_w4_kernel(const float* __restrict__ w0,
                                                     const float* __restrict__ w1,
                                                     const float* __restrict__ w2,
                                                     const float* __restrict__ w3,
                                                     f16* __restrict__ out) {
  int i = blockIdx.x * 256 + threadIdx.x;
  int t = i >> 17, r = i & 131071;
  const float* w = (t == 0) ? w0 : (t == 1) ? w1 : (t == 2) ? w2 : w3;
  const float4* p = (const float4*)(w + (size_t)r * 8);
  float4 a = p[0], b = p[1];
  f16x8 o = {(f16)a.x, (f16)a.y, (f16)a.z, (f16)a.w,
             (f16)b.x, (f16)b.y, (f16)b.z, (f16)b.w};
  *(f16x8*)(out + (size_t)t * 1048576 + (size_t)r * 8) = o;
}

// -------------------------------------------------- fused QKV GEMM, 2-phase
__global__ __launch_bounds__(256) void qkv_gemm_kernel(
    const f16* __restrict__ A, const f16* __restrict__ Wq,
    const f16* __restrict__ Wk, const f16* __restrict__ Wv,
    f16* __restrict__ Qo, f16* __restrict__ Ko, f16* __restrict__ VT) {
  __shared__ __align__(16) f16 As[2][128 * 64];
  __shared__ __align__(16) f16 Bs[2][128 * 64];
  const int bid = blockIdx.x + blockIdx.y * 8;
  const int swz = (bid & 7) * 80 + (bid >> 3);
  const int bx = swz & 7, y = swz >> 3;
  const f16* Bw;
  f16* Co = nullptr;
  int mt, isv = 0;
  if (y < 16) { Bw = Wq; Co = Qo; mt = (y & 7) | ((y >> 3) << 4); }
  else if (y < 48) { Bw = Wk; Co = Ko; mt = y - 16; }
  else { Bw = Wv; isv = 1; mt = y - 48; }
  const int m0 = mt * 128, n0 = bx * 128;
  const int tid = threadIdx.x, lane = tid & 63, w = tid >> 6;
  const int wr = w >> 1, wc = w & 1, g = lane >> 4, c = lane & 15;
  const int r_st = tid >> 3, t_st = tid & 7;

  auto stage = [&](int k0, int buf) {
#pragma unroll
    for (int i = 0; i < 4; ++i) {
      int row = r_st + i * 32;
      int sl = (t_st ^ (row & 7)) * 8;
      gld16(&A[(size_t)(m0 + row) * 1024 + k0 + sl], &As[buf][(row * 8 + t_st) * 8]);
      gld16(&Bw[(size_t)(n0 + row) * 1024 + k0 + sl], &Bs[buf][(row * 8 + t_st) * 8]);
    }
  };

  f32x4 acc[4][4] = {};

  stage(0, 0);
  __syncthreads();

  for (int t = 0; t < 16; ++t) {
    const int cur = t & 1;
    if (t < 15) stage((t + 1) * 64, cur ^ 1);
#pragma unroll
    for (int kb = 0; kb < 2; ++kb) {
      f16x8 af[4], bf[4];
#pragma unroll
      for (int m2 = 0; m2 < 4; ++m2)
        af[m2] = *(const f16x8*)&As[cur][(wr * 64 + m2 * 16 + c) * 64 +
                                         (((kb * 4 + g) ^ (c & 7)) * 8)];
#pragma unroll
      for (int nt = 0; nt < 4; ++nt)
        bf[nt] = *(const f16x8*)&Bs[cur][(wc * 64 + nt * 16 + c) * 64 +
                                         (((kb * 4 + g) ^ (c & 7)) * 8)];
#pragma unroll
      for (int m2 = 0; m2 < 4; ++m2)
#pragma unroll
        for (int nt = 0; nt < 4; ++nt)
          acc[m2][nt] = MFMA_F16(af[m2], bf[nt], acc[m2][nt]);
    }
    __syncthreads();
  }

  if (isv) {
    const int b = m0 >> 11;
    const int n_base = (m0 & 2047) + wr * 64 + g * 4;
#pragma unroll
    for (int m2 = 0; m2 < 4; ++m2)
#pragma unroll
      for (int nt = 0; nt < 4; ++nt) {
        int col = n0 + wc * 64 + nt * 16 + c;
        int h = col >> 6, d = col & 63;
        f16x4 pv = {(f16)acc[m2][nt][0], (f16)acc[m2][nt][1],
                    (f16)acc[m2][nt][2], (f16)acc[m2][nt][3]};
        *(f16x4*)&VT[((size_t)((b * 16 + h) * 64 + d)) * 2048 + n_base + m2 * 16] = pv;
      }
  } else {
#pragma unroll
    for (int m2 = 0; m2 < 4; ++m2)
#pragma unroll
      for (int nt = 0; nt < 4; ++nt) {
        int col = n0 + wc * 64 + nt * 16 + c;
#pragma unroll
        for (int r = 0; r < 4; ++r)
          Co[(size_t)(m0 + wr * 64 + m2 * 16 + g * 4 + r) * 1024 + col] =
              (f16)acc[m2][nt][r];
      }
  }
}

// ------------------------------------------------- proj GEMM 64x64, 2-phase
__global__ __launch_bounds__(256) void proj_gemm_kernel(
    const f16* __restrict__ A, const f16* __restrict__ Bw,
    float* __restrict__ C, const float* __restrict__ bias) {
  __shared__ __align__(16) f16 As[2][64 * 64];
  __shared__ __align__(16) f16 Bs[2][64 * 64];
  const int bid = blockIdx.x + blockIdx.y * 16;
  const int swz = (bid & 7) * 64 + (bid >> 3);
  const int m0 = (swz >> 4) * 64, n0 = (swz & 15) * 64;
  const int tid = threadIdx.x, lane = tid & 63, w = tid >> 6;
  const int wr = w >> 1, wc = w & 1, g = lane >> 4, c = lane & 15;
  const int r_st = tid >> 3, t_st = tid & 7;

  auto stage = [&](int k0, int buf) {
#pragma unroll
    for (int i = 0; i < 2; ++i) {
      int row = r_st + i * 32;
      int sl = (t_st ^ (row & 7)) * 8;
      gld16(&A[(size_t)(m0 + row) * 1024 + k0 + sl], &As[buf][(row * 8 + t_st) * 8]);
      gld16(&Bw[(size_t)(n0 + row) * 1024 + k0 + sl], &Bs[buf][(row * 8 + t_st) * 8]);
    }
  };

  f32x4 acc[2][2] = {};

  stage(0, 0);
  __syncthreads();

  for (int t = 0; t < 16; ++t) {
    const int cur = t & 1;
    if (t < 15) stage((t + 1) * 64, cur ^ 1);
#pragma unroll
    for (int kb = 0; kb < 2; ++kb) {
      f16x8 af[2], bf[2];
#pragma unroll
      for (int m2 = 0; m2 < 2; ++m2)
        af[m2] = *(const f16x8*)&As[cur][(wr * 32 + m2 * 16 + c) * 64 +
                                         (((kb * 4 + g) ^ (c & 7)) * 8)];
#pragma unroll
      for (int nt = 0; nt < 2; ++nt)
        bf[nt] = *(const f16x8*)&Bs[cur][(wc * 32 + nt * 16 + c) * 64 +
                                         (((kb * 4 + g) ^ (c & 7)) * 8)];
#pragma unroll
      for (int m2 = 0; m2 < 2; ++m2)
#pragma unroll
        for (int nt = 0; nt < 2; ++nt)
          acc[m2][nt] = MFMA_F16(af[m2], bf[nt], acc[m2][nt]);
    }
    __syncthreads();
  }

#pragma unroll
  for (int m2 = 0; m2 < 2; ++m2)
#pragma unroll
    for (int nt = 0; nt < 2; ++nt) {
      int col = n0 + wc * 32 + nt * 16 + c;
      float bv = bias[col];
#pragma unroll
      for (int r = 0; r < 4; ++r)
        C[(size_t)(m0 + wr * 32 + m2 * 16 + g * 4 + r) * 1024 + col] =
            acc[m2][nt][r] + bv;
    }
}

// -------------------------------------------------------------- attention
// mfma32 + register-P (R6-verified layouts) + LDS-staged coalesced K/V
// (R5-verified staging). 1024 blocks (16 qt x 16 h x 2 b x 2 ch, XCD-swz),
// 4 waves: (kh,qh) owns 32k x 32q per 64-KV-tile; each wave reads only its
// K/V halves from LDS ONCE (48KB/block-tile vs R5's 144KB). P stays in regs
// via cvt_pkrtz + shfl_xor(32). Epilogue cross-kh reduce overlays the K/V
// LDS (32KB total -> 4 blocks/CU resident, zero tail).
__global__ __launch_bounds__(256, 4) void attn_kernel(const f16* __restrict__ Q,
                                                      const f16* __restrict__ Kg,
                                                      const f16* __restrict__ VT,
                                                      f16* __restrict__ Opart,
                                                      float* __restrict__ ML) {
  __shared__ __align__(16) char smem[32768];
  f16* KsB = (f16*)smem;             // [2][64 k][64 d] swizzled
  f16* VsB = (f16*)(smem + 16384);   // [2][64 d][64 k] swizzled
  float* Ored = (float*)smem;        // overlay: [2 qh][64 d][32 q] f32
  float* Lred = (float*)(smem + 16384);  // [2 qh][2 kh][32 q]
  f16* Otr = (f16*)(smem + 16896);       // [2 qh][32 q][70]

  const int flat = blockIdx.x;
  const int swz = (flat & 7) * 128 + (flat >> 3);
  const int qt = swz & 15, h = (swz >> 4) & 15;
  const int ch = (swz >> 8) & 1, b = swz >> 9;
  const int tid = threadIdx.x, lane = tid & 63, w = tid >> 6;
  const int kh = w & 1, qh = w >> 1;
  const int l31 = lane & 31, h5 = lane >> 5;
  const bool lo = lane < 32;
  const int r_st = tid >> 3, t_st = tid & 7;

  const f16* Kbase = Kg + (size_t)(b * 2048 + ch * 1024) * 1024 + h * 64;
  const f16* Vbase = VT + ((size_t)((b * 16 + h) * 64)) * 2048 + ch * 1024;

  // Q fragments (B-operand for QK), scaled by SCALE*log2(e)
  f16x8 qf[4];
  {
    const f16* Qp =
        Q + (size_t)(b * 2048 + qt * 64 + qh * 32 + l31) * 1024 + h * 64 + h5 * 8;
#pragma unroll
    for (int ks = 0; ks < 4; ++ks) {
      qf[ks] = *(const f16x8*)(Qp + ks * 16);
#pragma unroll
      for (int j = 0; j < 8; ++j)
        qf[ks][j] = (f16)((float)qf[ks][j] * 0.1803368801f);
    }
  }

  auto stage = [&](int t, int buf) {
#pragma unroll
    for (int i = 0; i < 2; ++i) {
      int row = r_st + i * 32;
      int sl = (t_st ^ (row & 7)) * 8;
      gld16(&Kbase[(size_t)(t * 64 + row) * 1024 + sl],
            &KsB[buf * 4096 + (row * 8 + t_st) * 8]);
      gld16(&Vbase[(size_t)row * 2048 + t * 64 + sl],
            &VsB[buf * 4096 + (row * 8 + t_st) * 8]);
    }
  };

  f32x16 o0 = {}, o1 = {};
  float lp = 0.f;

  stage(0, 0);
  __syncthreads();

  const int krow = kh * 32 + l31;
  const int ksw = krow & 7;   // == l31 & 7
  const int vsw = l31 & 7;

  for (int t = 0; t < 16; ++t) {
    const int cur = t & 1;
    if (t < 15) stage(t + 1, cur ^ 1);

    // S^T[32k x 32q] = K-slice * Q^T (A = K from LDS, read once per wave)
    f32x16 s = {};
#pragma unroll
    for (int ks = 0; ks < 4; ++ks) {
      f16x8 ka =
          *(const f16x8*)&KsB[cur * 4096 + krow * 64 + (((2 * ks + h5) ^ ksw) * 8)];
      s = MFMA32(ka, qf[ks], s);
    }

    float e[16];
#pragma unroll
    for (int i = 0; i < 16; ++i) {
      e[i] = exp2f(s[i]);
      lp += e[i];
    }
    // pack P to f16 and redistribute C-layout -> B-layout (k=(l>>5)*8+j)
    int c01 = pkrtz(e[0], e[1]), c23 = pkrtz(e[2], e[3]);
    int c45 = pkrtz(e[4], e[5]), c67 = pkrtz(e[6], e[7]);
    int d01 = pkrtz(e[8], e[9]), d23 = pkrtz(e[10], e[11]);
    int d45 = pkrtz(e[12], e[13]), d67 = pkrtz(e[14], e[15]);
    int xc01 = __shfl_xor(c01, 32), xc23 = __shfl_xor(c23, 32);
    int xc45 = __shfl_xor(c45, 32), xc67 = __shfl_xor(c67, 32);
    int xd01 = __shfl_xor(d01, 32), xd23 = __shfl_xor(d23, 32);
    int xd45 = __shfl_xor(d45, 32), xd67 = __shfl_xor(d67, 32);
    U8 pb0, pb1;
    pb0.i[0] = lo ? c01 : xc45;
    pb0.i[1] = lo ? c23 : xc67;
    pb0.i[2] = lo ? xc01 : c45;
    pb0.i[3] = lo ? xc23 : c67;
    pb1.i[0] = lo ? d01 : xd45;
    pb1.i[1] = lo ? d23 : xd67;
    pb1.i[2] = lo ? xd01 : d45;
    pb1.i[3] = lo ? xd23 : d67;

    // O^T[64d x 32q] += V^T-slice * P (A = V from LDS, read once per wave)
#pragma unroll
    for (int kb = 0; kb < 2; ++kb) {
      int vs = (((4 * kh + 2 * kb + h5) ^ vsw) * 8);
      f16x8 va0 = *(const f16x8*)&VsB[cur * 4096 + l31 * 64 + vs];
      f16x8 va1 = *(const f16x8*)&VsB[cur * 4096 + (32 + l31) * 64 + vs];
      o0 = MFMA32(va0, kb ? pb1.v : pb0.v, o0);
      o1 = MFMA32(va1, kb ? pb1.v : pb0.v, o1);
    }
    __syncthreads();
  }

  // ---- epilogue (overlays K/V LDS): cross-kh reduce, normalize, store
  float l_own = lp + __shfl_xor(lp, 32);
  if (kh == 1) {
#pragma unroll
    for (int reg = 0; reg < 16; ++reg) {
      int row = (reg & 3) + 8 * (reg >> 2) + 4 * h5;
      Ored[qh * 2048 + row * 32 + l31] = o0[reg];
      Ored[qh * 2048 + (32 + row) * 32 + l31] = o1[reg];
    }
    if (lo) Lred[qh * 64 + 32 + l31] = l_own;
  } else {
    if (lo) Lred[qh * 64 + l31] = l_own;
  }
  __syncthreads();
  if (kh == 0) {
    float lt = Lred[qh * 64 + l31] + Lred[qh * 64 + 32 + l31];
    float li = 1.f / lt;
#pragma unroll
    for (int reg = 0; reg < 16; ++reg) {
      int row = (reg & 3) + 8 * (reg >> 2) + 4 * h5;
      Otr[(qh * 32 + l31) * 70 + row] =
          (f16)((o0[reg] + Ored[qh * 2048 + row * 32 + l31]) * li);
      Otr[(qh * 32 + l31) * 70 + 32 + row] =
          (f16)((o1[reg] + Ored[qh * 2048 + (32 + row) * 32 + l31]) * li);
    }
#pragma unroll
    for (int rep = 0; rep < 4; ++rep) {
      f16x8 ov =
          *(const f16x8*)&Otr[(qh * 32 + (lane >> 1)) * 70 + (lane & 1) * 32 + rep * 8];
      *(f16x8*)&Opart[(size_t)ch * 2097152 +
                      (size_t)(b * 1024 + qt * 64 + qh * 32 + (lane >> 1)) * 1024 +
                      h * 64 + (lane & 1) * 32 + rep * 8] = ov;
    }
    if (lo)
      ML[ch * 32768 + (b * 1024 + qt * 64 + qh * 32 + l31) * 16 + h] = lt;
  }
}

// -------------------------------------------------------------- combine (2 chunks)
__global__ __launch_bounds__(256) void combine_kernel(const f16* __restrict__ Opart,
                                                      const float* __restrict__ ML,
                                                      f16* __restrict__ O16) {
  int i = blockIdx.x * 256 + threadIdx.x;  // 262144 groups of 8
  int row = i >> 7;
  int h = (i & 127) >> 3;
  float l0 = ML[row * 16 + h];
  float l1 = ML[32768 + row * 16 + h];
  float inv = 1.f / (l0 + l1);
  f16x8 o0 = *(const f16x8*)&Opart[(size_t)i * 8];
  f16x8 o1 = *(const f16x8*)&Opart[2097152 + (size_t)i * 8];
  f16x8 r;
#pragma unroll
  for (int j = 0; j < 8; ++j)
    r[j] = (f16)((l0 * (float)o0[j] + l1 * (float)o1[j]) * inv);
  *(f16x8*)&O16[(size_t)i * 8] = r;
}

// ---------------------------------------------------------------- launcher
extern "C" void kernel_launch(void* const* d_in, const int* in_sizes, int n_in,
                              void* d_out, int out_size, void* d_ws, size_t ws_size,
                              hipStream_t stream) {
  const float* x = (const float*)d_in[0];
  const float* wq = (const float*)d_in[1];
  const float* wk = (const float*)d_in[2];
  const float* wv = (const float*)d_in[3];
  const float* wp = (const float*)d_in[4];
  const float* bp = (const float*)d_in[5];
  float* out = (float*)d_out;

  char* p = (char*)d_ws;
  f16* x16 = (f16*)p;   p += (size_t)4194304 * 2;      // ML aliases after GEMMs
  f16* w16 = (f16*)p;   p += (size_t)4 * 1048576 * 2;
  f16* Q16 = (f16*)p;   p += (size_t)4194304 * 2;
  f16* K16 = (f16*)p;   p += (size_t)4194304 * 2;
  f16* VT16 = (f16*)p;  p += (size_t)4194304 * 2;      // [B,H,D,N]
  f16* Opart = (f16*)p; p += (size_t)4194304 * 2;      // 2 chunks x [B*Nq, C]
  f16* O16 = (f16*)p;   p += (size_t)2097152 * 2;

  f16* wq16 = w16;
  f16* wk16 = w16 + 1048576;
  f16* wv16 = w16 + 2 * 1048576;
  f16* wp16 = w16 + 3 * 1048576;

  cvt_x_kernel<<<4194304 / 8 / 256, 256, 0, stream>>>(x, x16, 4194304 / 8);
  cvt_w4_kernel<<<4 * 131072 / 256, 256, 0, stream>>>(wq, wk, wv, wp, w16);

  qkv_gemm_kernel<<<dim3(8, 80), 256, 0, stream>>>(x16, wq16, wk16, wv16, Q16, K16,
                                                   VT16);

  float* MLp = (float*)x16;
  attn_kernel<<<dim3(1024), 256, 0, stream>>>(Q16, K16, VT16, Opart, MLp);
  combine_kernel<<<1024, 256, 0, stream>>>(Opart, MLp, O16);

  proj_gemm_kernel<<<dim3(16, 32), 256, 0, stream>>>(O16, wp16, out, bp);
}